// Round 4
// baseline (363.314 us; speedup 1.0000x reference)
//
#include <hip/hip_runtime.h>
#include <hip/hip_bf16.h>

typedef __bf16 bf16;
typedef __attribute__((__ext_vector_type__(8))) __bf16 bf16x8;
typedef __attribute__((__ext_vector_type__(4))) float f32x4;

#define MFMA16(a, b, c) __builtin_amdgcn_mfma_f32_16x16x32_bf16(a, b, c, 0, 0, 0)

static __device__ __forceinline__ bf16 f2b(float f) { return (bf16)f; }

// ---------------------------------------------------------------------------
// cast + transpose: in (R x Cc) f32 row-major -> out (Cc x R) bf16 row-major
// ---------------------------------------------------------------------------
__global__ __launch_bounds__(256) void cast_transpose(
    const float* __restrict__ in, bf16* __restrict__ out, int R, int Cc)
{
    __shared__ float tile[32][33];
    const int c0 = blockIdx.x * 32, r0 = blockIdx.y * 32;
    const int tx = threadIdx.x & 31, ty = threadIdx.x >> 5;
#pragma unroll
    for (int i = ty; i < 32; i += 8)
        tile[i][tx] = in[(size_t)(r0 + i) * Cc + c0 + tx];
    __syncthreads();
#pragma unroll
    for (int i = ty; i < 32; i += 8)
        out[(size_t)(c0 + i) * R + r0 + tx] = f2b(tile[tx][i]);
}

// ---------------------------------------------------------------------------
// QKV GEMM: X (8192 x 1024 f32) @ WqkvT^T (+bias) -> scatter q,k,v (bf16)
//   WqkvT: (3072 x 1024) bf16, row n holds k-contiguous weights
//   Qb, Kb: [bh][t][64] bf16 ; Vt: [bh][64][t] bf16 (transposed)
// ---------------------------------------------------------------------------
#define LDK 40

__global__ __launch_bounds__(256) void qkv_gemm(
    const float* __restrict__ X, const bf16* __restrict__ Wt,
    const float* __restrict__ bias,
    bf16* __restrict__ Qb, bf16* __restrict__ Kb, bf16* __restrict__ Vt)
{
    __shared__ __align__(16) bf16 As[128 * LDK];
    __shared__ __align__(16) bf16 Bs[128 * LDK];
    const int m0 = blockIdx.x * 128, n0 = blockIdx.y * 128;
    const int tid = threadIdx.x, lane = tid & 63, w = tid >> 6;
    const int wr = (w >> 1) * 64, wc = (w & 1) * 64;
    const int lg = lane >> 4, lr = lane & 15;
    const int sr = tid >> 1, sh = (tid & 1) * 16;
    f32x4 acc[4][4] = {};

    for (int k0 = 0; k0 < 1024; k0 += 32) {
        const float* xs = X + (size_t)(m0 + sr) * 1024 + k0 + sh;
        float4 a0 = *(const float4*)xs;
        float4 a1 = *(const float4*)(xs + 4);
        float4 a2 = *(const float4*)(xs + 8);
        float4 a3 = *(const float4*)(xs + 12);
        bf16x8 p0, p1;
        p0[0] = f2b(a0.x); p0[1] = f2b(a0.y); p0[2] = f2b(a0.z); p0[3] = f2b(a0.w);
        p0[4] = f2b(a1.x); p0[5] = f2b(a1.y); p0[6] = f2b(a1.z); p0[7] = f2b(a1.w);
        p1[0] = f2b(a2.x); p1[1] = f2b(a2.y); p1[2] = f2b(a2.z); p1[3] = f2b(a2.w);
        p1[4] = f2b(a3.x); p1[5] = f2b(a3.y); p1[6] = f2b(a3.z); p1[7] = f2b(a3.w);
        *(bf16x8*)(As + sr * LDK + sh) = p0;
        *(bf16x8*)(As + sr * LDK + sh + 8) = p1;
        const bf16* bs = Wt + (size_t)(n0 + sr) * 1024 + k0 + sh;
        *(int4*)(Bs + sr * LDK + sh)     = *(const int4*)bs;
        *(int4*)(Bs + sr * LDK + sh + 8) = *(const int4*)(bs + 8);
        __syncthreads();

        bf16x8 af[4], bfr[4];
#pragma unroll
        for (int m = 0; m < 4; ++m)
            af[m] = *(const bf16x8*)(As + (wr + m * 16 + lr) * LDK + lg * 8);
#pragma unroll
        for (int n = 0; n < 4; ++n)
            bfr[n] = *(const bf16x8*)(Bs + (wc + n * 16 + lr) * LDK + lg * 8);
#pragma unroll
        for (int m = 0; m < 4; ++m)
#pragma unroll
            for (int n = 0; n < 4; ++n)
                acc[m][n] = MFMA16(af[m], bfr[n], acc[m][n]);
        __syncthreads();
    }

#pragma unroll
    for (int m = 0; m < 4; ++m)
#pragma unroll
        for (int n = 0; n < 4; ++n)
#pragma unroll
            for (int j = 0; j < 4; ++j) {
                int gm = m0 + wr + m * 16 + lg * 4 + j;
                int gn = n0 + wc + n * 16 + lr;
                float v = acc[m][n][j] + bias[gn];
                int b = gm >> 11, t = gm & 2047;
                int which = gn >> 10, cc = gn & 1023;
                int h = cc >> 6, d = cc & 63;
                size_t bh = (size_t)(b * 16 + h);
                bf16 bv = f2b(v);
                if (which == 0)      Qb[(bh * 2048 + t) * 64 + d] = bv;
                else if (which == 1) Kb[(bh * 2048 + t) * 64 + d] = bv;
                else                 Vt[(bh * 64 + d) * 2048 + t] = bv;
            }
}

// ---------------------------------------------------------------------------
// Flash attention (causal): Qb,Kb [bh][t][64], Vt [bh][64][t] -> Yb [b][t][C]
// block: 64 q-rows for one (b,h); 4 waves x 16 rows each
// ---------------------------------------------------------------------------
__global__ __launch_bounds__(256) void attn(
    const bf16* __restrict__ Qb, const bf16* __restrict__ Kb,
    const bf16* __restrict__ Vt, bf16* __restrict__ Yb)
{
    __shared__ __align__(16) bf16 Ks[64 * 72];
    __shared__ __align__(16) bf16 Vs[64 * 72];
    __shared__ __align__(16) bf16 Ps[4][16 * 72];
    const int q0 = blockIdx.x * 64;
    const int bh = blockIdx.y;
    const int tid = threadIdx.x, lane = tid & 63, w = tid >> 6;
    const int lg = lane >> 4, lr = lane & 15;

    const bf16* qrow = Qb + ((size_t)bh * 2048 + q0 + w * 16 + lr) * 64;
    bf16x8 qf0 = *(const bf16x8*)(qrow + lg * 8);
    bf16x8 qf1 = *(const bf16x8*)(qrow + 32 + lg * 8);

    float m_[4], l_[4];
    f32x4 o[4] = {};
#pragma unroll
    for (int j = 0; j < 4; ++j) { m_[j] = -1e30f; l_[j] = 0.f; }

    const int sr = tid >> 2, sp = (tid & 3) * 16;
    const int ntiles = q0 / 64 + 1;
    for (int it = 0; it < ntiles; ++it) {
        const int j0 = it * 64;
        const bf16* ksrc = Kb + ((size_t)bh * 2048 + j0 + sr) * 64 + sp;
        *(int4*)(Ks + sr * 72 + sp)     = *(const int4*)ksrc;
        *(int4*)(Ks + sr * 72 + sp + 8) = *(const int4*)(ksrc + 8);
        const bf16* vsrc = Vt + ((size_t)bh * 64 + sr) * 2048 + j0 + sp;
        *(int4*)(Vs + sr * 72 + sp)     = *(const int4*)vsrc;
        *(int4*)(Vs + sr * 72 + sp + 8) = *(const int4*)(vsrc + 8);
        __syncthreads();

        f32x4 s[4];
#pragma unroll
        for (int n = 0; n < 4; ++n) {
            bf16x8 kf0 = *(const bf16x8*)(Ks + (n * 16 + lr) * 72 + lg * 8);
            bf16x8 kf1 = *(const bf16x8*)(Ks + (n * 16 + lr) * 72 + 32 + lg * 8);
            f32x4 z = {};
            z = MFMA16(qf0, kf0, z);
            z = MFMA16(qf1, kf1, z);
            s[n] = z;
        }

        float tmax[4] = {-1e30f, -1e30f, -1e30f, -1e30f};
        const int qrb = q0 + w * 16 + lg * 4;
#pragma unroll
        for (int n = 0; n < 4; ++n)
#pragma unroll
            for (int j = 0; j < 4; ++j) {
                float sv = s[n][j] * 0.125f;
                if (j0 + n * 16 + lr > qrb + j) sv = -1e30f;
                s[n][j] = sv;
                tmax[j] = fmaxf(tmax[j], sv);
            }
#pragma unroll
        for (int d = 1; d < 16; d <<= 1)
#pragma unroll
            for (int j = 0; j < 4; ++j)
                tmax[j] = fmaxf(tmax[j], __shfl_xor(tmax[j], d));

        float corr[4], tsum[4];
#pragma unroll
        for (int j = 0; j < 4; ++j) {
            float mn = fmaxf(m_[j], tmax[j]);
            corr[j] = __expf(m_[j] - mn);
            m_[j] = mn;
            tsum[j] = 0.f;
        }
#pragma unroll
        for (int n = 0; n < 4; ++n)
#pragma unroll
            for (int j = 0; j < 4; ++j) {
                float p = __expf(s[n][j] - m_[j]);
                tsum[j] += p;
                Ps[w][(lg * 4 + j) * 72 + n * 16 + lr] = f2b(p);
            }
#pragma unroll
        for (int d = 1; d < 16; d <<= 1)
#pragma unroll
            for (int j = 0; j < 4; ++j)
                tsum[j] += __shfl_xor(tsum[j], d);
#pragma unroll
        for (int j = 0; j < 4; ++j) l_[j] = l_[j] * corr[j] + tsum[j];
#pragma unroll
        for (int n = 0; n < 4; ++n)
#pragma unroll
            for (int j = 0; j < 4; ++j) o[n][j] *= corr[j];

        bf16x8 pf0 = *(const bf16x8*)(&Ps[w][lr * 72 + lg * 8]);
        bf16x8 pf1 = *(const bf16x8*)(&Ps[w][lr * 72 + 32 + lg * 8]);
#pragma unroll
        for (int n = 0; n < 4; ++n) {
            bf16x8 vf0 = *(const bf16x8*)(Vs + (n * 16 + lr) * 72 + lg * 8);
            bf16x8 vf1 = *(const bf16x8*)(Vs + (n * 16 + lr) * 72 + 32 + lg * 8);
            o[n] = MFMA16(pf0, vf0, o[n]);
            o[n] = MFMA16(pf1, vf1, o[n]);
        }
        __syncthreads();
    }

    const int b = bh >> 4, h = bh & 15;
#pragma unroll
    for (int n = 0; n < 4; ++n)
#pragma unroll
        for (int j = 0; j < 4; ++j) {
            int qr = q0 + w * 16 + lg * 4 + j;
            float ov = o[n][j] / l_[j];
            Yb[((size_t)b * 2048 + qr) * 1024 + h * 64 + n * 16 + lr] = f2b(ov);
        }
}

// ---------------------------------------------------------------------------
// Out GEMM: Yb (8192 x 1024 bf16) @ WoutT^T + bias -> Out f32
// ---------------------------------------------------------------------------
__global__ __launch_bounds__(256) void out_gemm(
    const bf16* __restrict__ Y, const bf16* __restrict__ Wt,
    const float* __restrict__ bias, float* __restrict__ Out)
{
    __shared__ __align__(16) bf16 As[128 * LDK];
    __shared__ __align__(16) bf16 Bs[128 * LDK];
    const int m0 = blockIdx.x * 128, n0 = blockIdx.y * 128;
    const int tid = threadIdx.x, lane = tid & 63, w = tid >> 6;
    const int wr = (w >> 1) * 64, wc = (w & 1) * 64;
    const int lg = lane >> 4, lr = lane & 15;
    const int sr = tid >> 1, sh = (tid & 1) * 16;
    f32x4 acc[4][4] = {};

    for (int k0 = 0; k0 < 1024; k0 += 32) {
        const bf16* ys = Y + (size_t)(m0 + sr) * 1024 + k0 + sh;
        *(int4*)(As + sr * LDK + sh)     = *(const int4*)ys;
        *(int4*)(As + sr * LDK + sh + 8) = *(const int4*)(ys + 8);
        const bf16* bs = Wt + (size_t)(n0 + sr) * 1024 + k0 + sh;
        *(int4*)(Bs + sr * LDK + sh)     = *(const int4*)bs;
        *(int4*)(Bs + sr * LDK + sh + 8) = *(const int4*)(bs + 8);
        __syncthreads();

        bf16x8 af[4], bfr[4];
#pragma unroll
        for (int m = 0; m < 4; ++m)
            af[m] = *(const bf16x8*)(As + (wr + m * 16 + lr) * LDK + lg * 8);
#pragma unroll
        for (int n = 0; n < 4; ++n)
            bfr[n] = *(const bf16x8*)(Bs + (wc + n * 16 + lr) * LDK + lg * 8);
#pragma unroll
        for (int m = 0; m < 4; ++m)
#pragma unroll
            for (int n = 0; n < 4; ++n)
                acc[m][n] = MFMA16(af[m], bfr[n], acc[m][n]);
        __syncthreads();
    }

#pragma unroll
    for (int m = 0; m < 4; ++m)
#pragma unroll
        for (int n = 0; n < 4; ++n)
#pragma unroll
            for (int j = 0; j < 4; ++j) {
                int gm = m0 + wr + m * 16 + lg * 4 + j;
                int gn = n0 + wc + n * 16 + lr;
                Out[(size_t)gm * 1024 + gn] = acc[m][n][j] + bias[gn];
            }
}

// ---------------------------------------------------------------------------
extern "C" void kernel_launch(void* const* d_in, const int* in_sizes, int n_in,
                              void* d_out, int out_size, void* d_ws, size_t ws_size,
                              hipStream_t stream)
{
    const float* x     = (const float*)d_in[0];
    const float* w_qkv = (const float*)d_in[1];
    const float* b_qkv = (const float*)d_in[2];
    const float* w_out = (const float*)d_in[3];
    const float* b_out = (const float*)d_in[4];
    float* out = (float*)d_out;

    char* ws = (char*)d_ws;
    bf16* wqkvT = (bf16*)(ws);                                  //  6,291,456 B
    bf16* woutT = (bf16*)(ws + 6291456);                        //  2,097,152 B
    bf16* Qb    = (bf16*)(ws + 6291456 + 2097152);              // 16,777,216 B
    bf16* Kb    = (bf16*)(ws + 6291456 + 2097152 + 16777216);   // 16,777,216 B
    bf16* Vt    = (bf16*)(ws + 6291456 + 2097152 + 2u * 16777216u); // 16 MB
    bf16* Yb    = (bf16*)(ws + 6291456 + 2097152 + 3u * 16777216u); // 16 MB

    cast_transpose<<<dim3(96, 32), 256, 0, stream>>>(w_qkv, wqkvT, 1024, 3072);
    cast_transpose<<<dim3(32, 32), 256, 0, stream>>>(w_out, woutT, 1024, 1024);
    qkv_gemm<<<dim3(64, 24), 256, 0, stream>>>(x, wqkvT, b_qkv, Qb, Kb, Vt);
    attn<<<dim3(32, 64), 256, 0, stream>>>(Qb, Kb, Vt, Yb);
    out_gemm<<<dim3(64, 8), 256, 0, stream>>>(Yb, woutT, b_out, out);
}

// Round 5
// 281.093 us; speedup vs baseline: 1.2925x; 1.2925x over previous
//
#include <hip/hip_runtime.h>
#include <hip/hip_bf16.h>

typedef __bf16 bf16;
typedef __attribute__((__ext_vector_type__(8))) __bf16 bf16x8;
typedef __attribute__((__ext_vector_type__(4))) float f32x4;

#define MFMA16(a, b, c) __builtin_amdgcn_mfma_f32_16x16x32_bf16(a, b, c, 0, 0, 0)

static __device__ __forceinline__ bf16 f2b(float f) { return (bf16)f; }

// ---------------------------------------------------------------------------
// cast + transpose: in (R x Cc) f32 row-major -> out (Cc x R) bf16 row-major
// ---------------------------------------------------------------------------
__global__ __launch_bounds__(256) void cast_transpose(
    const float* __restrict__ in, bf16* __restrict__ out, int R, int Cc)
{
    __shared__ float tile[32][33];
    const int c0 = blockIdx.x * 32, r0 = blockIdx.y * 32;
    const int tx = threadIdx.x & 31, ty = threadIdx.x >> 5;
#pragma unroll
    for (int i = ty; i < 32; i += 8)
        tile[i][tx] = in[(size_t)(r0 + i) * Cc + c0 + tx];
    __syncthreads();
#pragma unroll
    for (int i = ty; i < 32; i += 8)
        out[(size_t)(c0 + i) * R + r0 + tx] = f2b(tile[tx][i]);
}

// ---------------------------------------------------------------------------
// QKV GEMM: X (8192 x 1024 f32) @ WqkvT^T (+bias) -> scatter q,k,v (bf16)
// ---------------------------------------------------------------------------
#define LDK 40

__global__ __launch_bounds__(256) void qkv_gemm(
    const float* __restrict__ X, const bf16* __restrict__ Wt,
    const float* __restrict__ bias,
    bf16* __restrict__ Qb, bf16* __restrict__ Kb, bf16* __restrict__ Vt)
{
    __shared__ __align__(16) bf16 As[128 * LDK];
    __shared__ __align__(16) bf16 Bs[128 * LDK];
    const int m0 = blockIdx.x * 128, n0 = blockIdx.y * 128;
    const int tid = threadIdx.x, lane = tid & 63, w = tid >> 6;
    const int wr = (w >> 1) * 64, wc = (w & 1) * 64;
    const int lg = lane >> 4, lr = lane & 15;
    const int sr = tid >> 1, sh = (tid & 1) * 16;
    f32x4 acc[4][4] = {};

    for (int k0 = 0; k0 < 1024; k0 += 32) {
        const float* xs = X + (size_t)(m0 + sr) * 1024 + k0 + sh;
        float4 a0 = *(const float4*)xs;
        float4 a1 = *(const float4*)(xs + 4);
        float4 a2 = *(const float4*)(xs + 8);
        float4 a3 = *(const float4*)(xs + 12);
        bf16x8 p0, p1;
        p0[0] = f2b(a0.x); p0[1] = f2b(a0.y); p0[2] = f2b(a0.z); p0[3] = f2b(a0.w);
        p0[4] = f2b(a1.x); p0[5] = f2b(a1.y); p0[6] = f2b(a1.z); p0[7] = f2b(a1.w);
        p1[0] = f2b(a2.x); p1[1] = f2b(a2.y); p1[2] = f2b(a2.z); p1[3] = f2b(a2.w);
        p1[4] = f2b(a3.x); p1[5] = f2b(a3.y); p1[6] = f2b(a3.z); p1[7] = f2b(a3.w);
        *(bf16x8*)(As + sr * LDK + sh) = p0;
        *(bf16x8*)(As + sr * LDK + sh + 8) = p1;
        const bf16* bs = Wt + (size_t)(n0 + sr) * 1024 + k0 + sh;
        *(int4*)(Bs + sr * LDK + sh)     = *(const int4*)bs;
        *(int4*)(Bs + sr * LDK + sh + 8) = *(const int4*)(bs + 8);
        __syncthreads();

        bf16x8 af[4], bfr[4];
#pragma unroll
        for (int m = 0; m < 4; ++m)
            af[m] = *(const bf16x8*)(As + (wr + m * 16 + lr) * LDK + lg * 8);
#pragma unroll
        for (int n = 0; n < 4; ++n)
            bfr[n] = *(const bf16x8*)(Bs + (wc + n * 16 + lr) * LDK + lg * 8);
#pragma unroll
        for (int m = 0; m < 4; ++m)
#pragma unroll
            for (int n = 0; n < 4; ++n)
                acc[m][n] = MFMA16(af[m], bfr[n], acc[m][n]);
        __syncthreads();
    }

#pragma unroll
    for (int m = 0; m < 4; ++m)
#pragma unroll
        for (int n = 0; n < 4; ++n)
#pragma unroll
            for (int j = 0; j < 4; ++j) {
                int gm = m0 + wr + m * 16 + lg * 4 + j;
                int gn = n0 + wc + n * 16 + lr;
                float v = acc[m][n][j] + bias[gn];
                int b = gm >> 11, t = gm & 2047;
                int which = gn >> 10, cc = gn & 1023;
                int h = cc >> 6, d = cc & 63;
                size_t bh = (size_t)(b * 16 + h);
                bf16 bv = f2b(v);
                if (which == 0)      Qb[(bh * 2048 + t) * 64 + d] = bv;
                else if (which == 1) Kb[(bh * 2048 + t) * 64 + d] = bv;
                else                 Vt[(bh * 64 + d) * 2048 + t] = bv;
            }
}

// ---------------------------------------------------------------------------
// Flash attention (causal), triangle-paired blocks:
//   block (pair, bh) processes q-tiles ia=pair and ib=31-pair, sharing the
//   KV staging loop (tiles 0..ib). Every block does exactly 33 tile-computes.
//   l is accumulated via a ones-column MFMA (row 64 of Vs == 1.0).
// ---------------------------------------------------------------------------
__global__ __launch_bounds__(256) void attn(
    const bf16* __restrict__ Qb, const bf16* __restrict__ Kb,
    const bf16* __restrict__ Vt, bf16* __restrict__ Yb)
{
    __shared__ __align__(16) bf16 Ks[64 * 72];
    __shared__ __align__(16) bf16 Vs[80 * 72];   // rows 64..79: ones row + zeros
    __shared__ __align__(16) bf16 Ps[4][16 * 72];
    const int pair = blockIdx.x;                 // 0..15
    const int bh = blockIdx.y;
    const int ia = pair, ib = 31 - pair;
    const int q0A = ia * 64, q0B = ib * 64;
    const int tid = threadIdx.x, lane = tid & 63, w = tid >> 6;
    const int lg = lane >> 4, lr = lane & 15;
    const float SC = 0.125f * 1.44269504f;       // 1/sqrt(64) * log2(e)

    const bf16* qrA = Qb + ((size_t)bh * 2048 + q0A + w * 16 + lr) * 64;
    bf16x8 qA0 = *(const bf16x8*)(qrA + lg * 8);
    bf16x8 qA1 = *(const bf16x8*)(qrA + 32 + lg * 8);
    const bf16* qrB = Qb + ((size_t)bh * 2048 + q0B + w * 16 + lr) * 64;
    bf16x8 qB0 = *(const bf16x8*)(qrB + lg * 8);
    bf16x8 qB1 = *(const bf16x8*)(qrB + 32 + lg * 8);

    float mA[4], mB[4];
    f32x4 oA[4] = {}, oB[4] = {};
    f32x4 lA = {}, lB = {};                      // l accumulators (col 64)
#pragma unroll
    for (int j = 0; j < 4; ++j) { mA[j] = -1e30f; mB[j] = -1e30f; }

    // init ones row (d=64) and zero rows 65..79 (avoid NaN garbage in MFMA)
    for (int i = tid; i < 16 * 72; i += 256) {
        int r = i / 72, c = i % 72;
        Vs[(64 + r) * 72 + c] = (r == 0) ? (bf16)1.0f : (bf16)0.0f;
    }

    const int sr = tid >> 2, sp = (tid & 3) * 16;

    auto phase = [&](bf16x8 qf0, bf16x8 qf1, f32x4 (&o)[4], f32x4& l4,
                     float (&m_)[4], int q0, bool diag, int j0) {
        f32x4 s[4];
#pragma unroll
        for (int n = 0; n < 4; ++n) {
            bf16x8 kf0 = *(const bf16x8*)(Ks + (n * 16 + lr) * 72 + lg * 8);
            bf16x8 kf1 = *(const bf16x8*)(Ks + (n * 16 + lr) * 72 + 32 + lg * 8);
            f32x4 z = {};
            z = MFMA16(qf0, kf0, z);
            z = MFMA16(qf1, kf1, z);
            s[n] = z;
        }
        float tmax[4] = {-1e30f, -1e30f, -1e30f, -1e30f};
        if (diag) {
            const int qrb = q0 + w * 16 + lg * 4;
#pragma unroll
            for (int n = 0; n < 4; ++n)
#pragma unroll
                for (int j = 0; j < 4; ++j) {
                    float sv = s[n][j] * SC;
                    if (j0 + n * 16 + lr > qrb + j) sv = -1e30f;
                    s[n][j] = sv;
                    tmax[j] = fmaxf(tmax[j], sv);
                }
        } else {
#pragma unroll
            for (int n = 0; n < 4; ++n)
#pragma unroll
                for (int j = 0; j < 4; ++j) {
                    float sv = s[n][j] * SC;
                    s[n][j] = sv;
                    tmax[j] = fmaxf(tmax[j], sv);
                }
        }
#pragma unroll
        for (int d = 1; d < 16; d <<= 1)
#pragma unroll
            for (int j = 0; j < 4; ++j)
                tmax[j] = fmaxf(tmax[j], __shfl_xor(tmax[j], d));

        // defer-max (T13): skip rescale when growth <= 8 (in log2 domain)
        bool ok = (tmax[0] <= m_[0] + 8.f) && (tmax[1] <= m_[1] + 8.f) &&
                  (tmax[2] <= m_[2] + 8.f) && (tmax[3] <= m_[3] + 8.f);
        if (!__all(ok)) {
#pragma unroll
            for (int j = 0; j < 4; ++j) {
                float mn = fmaxf(m_[j], tmax[j]);
                float corr = exp2f(m_[j] - mn);
                m_[j] = mn;
                l4[j] *= corr;
#pragma unroll
                for (int n = 0; n < 4; ++n) o[n][j] *= corr;
            }
        }
#pragma unroll
        for (int n = 0; n < 4; ++n)
#pragma unroll
            for (int j = 0; j < 4; ++j) {
                float p = exp2f(s[n][j] - m_[j]);
                Ps[w][(lg * 4 + j) * 72 + n * 16 + lr] = f2b(p);
            }
        bf16x8 pf0 = *(const bf16x8*)(&Ps[w][lr * 72 + lg * 8]);
        bf16x8 pf1 = *(const bf16x8*)(&Ps[w][lr * 72 + 32 + lg * 8]);
        bf16x8 e0 = *(const bf16x8*)(Vs + (64 + lr) * 72 + lg * 8);
        bf16x8 e1 = *(const bf16x8*)(Vs + (64 + lr) * 72 + 32 + lg * 8);
        l4 = MFMA16(pf0, e0, l4);
        l4 = MFMA16(pf1, e1, l4);
#pragma unroll
        for (int n = 0; n < 4; ++n) {
            bf16x8 vf0 = *(const bf16x8*)(Vs + (n * 16 + lr) * 72 + lg * 8);
            bf16x8 vf1 = *(const bf16x8*)(Vs + (n * 16 + lr) * 72 + 32 + lg * 8);
            o[n] = MFMA16(pf0, vf0, o[n]);
            o[n] = MFMA16(pf1, vf1, o[n]);
        }
    };

    const int ntiles = ib + 1;
    for (int it = 0; it < ntiles; ++it) {
        const int j0 = it * 64;
        const bf16* ksrc = Kb + ((size_t)bh * 2048 + j0 + sr) * 64 + sp;
        *(int4*)(Ks + sr * 72 + sp)     = *(const int4*)ksrc;
        *(int4*)(Ks + sr * 72 + sp + 8) = *(const int4*)(ksrc + 8);
        const bf16* vsrc = Vt + ((size_t)bh * 64 + sr) * 2048 + j0 + sp;
        *(int4*)(Vs + sr * 72 + sp)     = *(const int4*)vsrc;
        *(int4*)(Vs + sr * 72 + sp + 8) = *(const int4*)(vsrc + 8);
        __syncthreads();

        phase(qB0, qB1, oB, lB, mB, q0B, it == ib, j0);
        if (it <= ia) phase(qA0, qA1, oA, lA, mA, q0A, it == ia, j0);
        __syncthreads();
    }

    const int b = bh >> 4, h = bh & 15;
    auto wout = [&](f32x4 (&o)[4], f32x4& l4, int q0) {
        float inv[4];
#pragma unroll
        for (int j = 0; j < 4; ++j) {
            float lv = __shfl(l4[j], (lane & 48));   // broadcast from lr==0 lane
            inv[j] = 1.f / lv;
        }
#pragma unroll
        for (int n = 0; n < 4; ++n)
#pragma unroll
            for (int j = 0; j < 4; ++j) {
                int qr = q0 + w * 16 + lg * 4 + j;
                Yb[((size_t)b * 2048 + qr) * 1024 + h * 64 + n * 16 + lr] =
                    f2b(o[n][j] * inv[j]);
            }
    };
    wout(oA, lA, q0A);
    wout(oB, lB, q0B);
}

// ---------------------------------------------------------------------------
// Out GEMM: Yb (8192 x 1024 bf16) @ WoutT^T + bias -> Out f32
// ---------------------------------------------------------------------------
__global__ __launch_bounds__(256) void out_gemm(
    const bf16* __restrict__ Y, const bf16* __restrict__ Wt,
    const float* __restrict__ bias, float* __restrict__ Out)
{
    __shared__ __align__(16) bf16 As[128 * LDK];
    __shared__ __align__(16) bf16 Bs[128 * LDK];
    const int m0 = blockIdx.x * 128, n0 = blockIdx.y * 128;
    const int tid = threadIdx.x, lane = tid & 63, w = tid >> 6;
    const int wr = (w >> 1) * 64, wc = (w & 1) * 64;
    const int lg = lane >> 4, lr = lane & 15;
    const int sr = tid >> 1, sh = (tid & 1) * 16;
    f32x4 acc[4][4] = {};

    for (int k0 = 0; k0 < 1024; k0 += 32) {
        const bf16* ys = Y + (size_t)(m0 + sr) * 1024 + k0 + sh;
        *(int4*)(As + sr * LDK + sh)     = *(const int4*)ys;
        *(int4*)(As + sr * LDK + sh + 8) = *(const int4*)(ys + 8);
        const bf16* bs = Wt + (size_t)(n0 + sr) * 1024 + k0 + sh;
        *(int4*)(Bs + sr * LDK + sh)     = *(const int4*)bs;
        *(int4*)(Bs + sr * LDK + sh + 8) = *(const int4*)(bs + 8);
        __syncthreads();

        bf16x8 af[4], bfr[4];
#pragma unroll
        for (int m = 0; m < 4; ++m)
            af[m] = *(const bf16x8*)(As + (wr + m * 16 + lr) * LDK + lg * 8);
#pragma unroll
        for (int n = 0; n < 4; ++n)
            bfr[n] = *(const bf16x8*)(Bs + (wc + n * 16 + lr) * LDK + lg * 8);
#pragma unroll
        for (int m = 0; m < 4; ++m)
#pragma unroll
            for (int n = 0; n < 4; ++n)
                acc[m][n] = MFMA16(af[m], bfr[n], acc[m][n]);
        __syncthreads();
    }

#pragma unroll
    for (int m = 0; m < 4; ++m)
#pragma unroll
        for (int n = 0; n < 4; ++n)
#pragma unroll
            for (int j = 0; j < 4; ++j) {
                int gm = m0 + wr + m * 16 + lg * 4 + j;
                int gn = n0 + wc + n * 16 + lr;
                Out[(size_t)gm * 1024 + gn] = acc[m][n][j] + bias[gn];
            }
}

// ---------------------------------------------------------------------------
extern "C" void kernel_launch(void* const* d_in, const int* in_sizes, int n_in,
                              void* d_out, int out_size, void* d_ws, size_t ws_size,
                              hipStream_t stream)
{
    const float* x     = (const float*)d_in[0];
    const float* w_qkv = (const float*)d_in[1];
    const float* b_qkv = (const float*)d_in[2];
    const float* w_out = (const float*)d_in[3];
    const float* b_out = (const float*)d_in[4];
    float* out = (float*)d_out;

    char* ws = (char*)d_ws;
    bf16* wqkvT = (bf16*)(ws);
    bf16* woutT = (bf16*)(ws + 6291456);
    bf16* Qb    = (bf16*)(ws + 6291456 + 2097152);
    bf16* Kb    = (bf16*)(ws + 6291456 + 2097152 + 16777216);
    bf16* Vt    = (bf16*)(ws + 6291456 + 2097152 + 2u * 16777216u);
    bf16* Yb    = (bf16*)(ws + 6291456 + 2097152 + 3u * 16777216u);

    cast_transpose<<<dim3(96, 32), 256, 0, stream>>>(w_qkv, wqkvT, 1024, 3072);
    cast_transpose<<<dim3(32, 32), 256, 0, stream>>>(w_out, woutT, 1024, 1024);
    qkv_gemm<<<dim3(64, 24), 256, 0, stream>>>(x, wqkvT, b_qkv, Qb, Kb, Vt);
    attn<<<dim3(16, 64), 256, 0, stream>>>(Qb, Kb, Vt, Yb);
    out_gemm<<<dim3(64, 8), 256, 0, stream>>>(Yb, woutT, b_out, out);
}

// Round 6
// 278.896 us; speedup vs baseline: 1.3027x; 1.0079x over previous
//
#include <hip/hip_runtime.h>
#include <hip/hip_bf16.h>

typedef __bf16 bf16;
typedef __attribute__((__ext_vector_type__(4))) __bf16 bf16x4;
typedef __attribute__((__ext_vector_type__(8))) __bf16 bf16x8;
typedef __attribute__((__ext_vector_type__(4))) float f32x4;

#define MFMA16(a, b, c) __builtin_amdgcn_mfma_f32_16x16x32_bf16(a, b, c, 0, 0, 0)

static __device__ __forceinline__ bf16 f2b(float f) { return (bf16)f; }

// async global->LDS, 16B per lane. Dest must be wave-uniform base (+lane*16 HW).
static __device__ __forceinline__ void gload16(const void* g, void* l) {
    __builtin_amdgcn_global_load_lds(
        (const __attribute__((address_space(1))) int*)g,
        (__attribute__((address_space(3))) int*)l, 16, 0, 0);
}

// ---------------------------------------------------------------------------
// xcast: f32 -> bf16 bulk cast (X -> Xb), 16 elems/thread
// ---------------------------------------------------------------------------
__global__ __launch_bounds__(256) void xcast(
    const float* __restrict__ in, bf16* __restrict__ out)
{
    size_t i = ((size_t)blockIdx.x * 256 + threadIdx.x) * 16;
    float4 a0 = *(const float4*)(in + i);
    float4 a1 = *(const float4*)(in + i + 4);
    float4 a2 = *(const float4*)(in + i + 8);
    float4 a3 = *(const float4*)(in + i + 12);
    bf16x8 p0, p1;
    p0[0] = f2b(a0.x); p0[1] = f2b(a0.y); p0[2] = f2b(a0.z); p0[3] = f2b(a0.w);
    p0[4] = f2b(a1.x); p0[5] = f2b(a1.y); p0[6] = f2b(a1.z); p0[7] = f2b(a1.w);
    p1[0] = f2b(a2.x); p1[1] = f2b(a2.y); p1[2] = f2b(a2.z); p1[3] = f2b(a2.w);
    p1[4] = f2b(a3.x); p1[5] = f2b(a3.y); p1[6] = f2b(a3.z); p1[7] = f2b(a3.w);
    *(bf16x8*)(out + i) = p0;
    *(bf16x8*)(out + i + 8) = p1;
}

// ---------------------------------------------------------------------------
// cast + transpose: in (R x Cc) f32 row-major -> out (Cc x R) bf16 row-major
// ---------------------------------------------------------------------------
__global__ __launch_bounds__(256) void cast_transpose(
    const float* __restrict__ in, bf16* __restrict__ out, int R, int Cc)
{
    __shared__ float tile[32][33];
    const int c0 = blockIdx.x * 32, r0 = blockIdx.y * 32;
    const int tx = threadIdx.x & 31, ty = threadIdx.x >> 5;
#pragma unroll
    for (int i = ty; i < 32; i += 8)
        tile[i][tx] = in[(size_t)(r0 + i) * Cc + c0 + tx];
    __syncthreads();
#pragma unroll
    for (int i = ty; i < 32; i += 8)
        out[(size_t)(c0 + i) * R + r0 + tx] = f2b(tile[tx][i]);
}

// ---------------------------------------------------------------------------
// QKV GEMM (m97-style): Xb (8192x1024 bf16) @ WqkvT^T + bias -> Qb,Kb,Vt
//   linear LDS [128][32], global_load_lds width-16 staging
// ---------------------------------------------------------------------------
__global__ __launch_bounds__(256) void qkv_gemm(
    const bf16* __restrict__ Xb, const bf16* __restrict__ Wt,
    const float* __restrict__ bias,
    bf16* __restrict__ Qb, bf16* __restrict__ Kb, bf16* __restrict__ Vt)
{
    __shared__ __align__(16) bf16 As[128 * 32];
    __shared__ __align__(16) bf16 Bs[128 * 32];
    const int m0 = blockIdx.x * 128, n0 = blockIdx.y * 128;
    const int tid = threadIdx.x, lane = tid & 63, w = tid >> 6;
    const int wr = (w >> 1) * 64, wc = (w & 1) * 64;
    const int lg = lane >> 4, lr = lane & 15;
    const int srow = tid >> 2, scol = (tid & 3) * 8;   // stage row/col (elems)
    f32x4 acc[4][4] = {};

    for (int k0 = 0; k0 < 1024; k0 += 32) {
#pragma unroll
        for (int half = 0; half < 2; ++half) {
            const int r = srow + half * 64;
            gload16(Xb + (size_t)(m0 + r) * 1024 + k0 + scol,
                    As + half * 2048 + w * 512);
            gload16(Wt + (size_t)(n0 + r) * 1024 + k0 + scol,
                    Bs + half * 2048 + w * 512);
        }
        __syncthreads();

        bf16x8 af[4], bfr[4];
#pragma unroll
        for (int m = 0; m < 4; ++m)
            af[m] = *(const bf16x8*)(As + (wr + m * 16 + lr) * 32 + lg * 8);
#pragma unroll
        for (int n = 0; n < 4; ++n)
            bfr[n] = *(const bf16x8*)(Bs + (wc + n * 16 + lr) * 32 + lg * 8);
#pragma unroll
        for (int m = 0; m < 4; ++m)
#pragma unroll
            for (int n = 0; n < 4; ++n)
                acc[m][n] = MFMA16(af[m], bfr[n], acc[m][n]);
        __syncthreads();
    }

#pragma unroll
    for (int m = 0; m < 4; ++m)
#pragma unroll
        for (int n = 0; n < 4; ++n) {
            int gn = n0 + wc + n * 16 + lr;
            int which = gn >> 10, cc = gn & 1023;
            int h = cc >> 6, d = cc & 63;
            float bv = bias[gn];
            if (which == 2) {
                // V: pack 4 adjacent-t values -> one b64 store into Vt[bh][d][t]
                int gm0 = m0 + wr + m * 16 + lg * 4;
                int b = gm0 >> 11, t0 = gm0 & 2047;
                size_t bh = (size_t)(b * 16 + h);
                bf16x4 pk;
#pragma unroll
                for (int j = 0; j < 4; ++j) pk[j] = f2b(acc[m][n][j] + bv);
                *(bf16x4*)(Vt + (bh * 64 + d) * 2048 + t0) = pk;
            } else {
#pragma unroll
                for (int j = 0; j < 4; ++j) {
                    int gm = m0 + wr + m * 16 + lg * 4 + j;
                    int b = gm >> 11, t = gm & 2047;
                    size_t bh = (size_t)(b * 16 + h);
                    bf16 v = f2b(acc[m][n][j] + bv);
                    if (which == 0) Qb[(bh * 2048 + t) * 64 + d] = v;
                    else            Kb[(bh * 2048 + t) * 64 + d] = v;
                }
            }
        }
}

// ---------------------------------------------------------------------------
// Flash attention (causal), triangle-paired, SWAPPED QK^T (S^T = K·Q):
//   lane holds full 64-k score slice for ONE q-row (q = lane&15) per phase ->
//   in-lane max/sum, 2 shuffles, b64 P writes. l,m are per-lane scalars.
// ---------------------------------------------------------------------------
__global__ __launch_bounds__(256, 4) void attn(
    const bf16* __restrict__ Qb, const bf16* __restrict__ Kb,
    const bf16* __restrict__ Vt, bf16* __restrict__ Yb)
{
    __shared__ __align__(16) bf16 Ks[64 * 72];
    __shared__ __align__(16) bf16 Vs[64 * 72];
    __shared__ __align__(16) bf16 Ps[4][16 * 72];
    const int pair = blockIdx.x;                 // 0..15
    const int bh = blockIdx.y;
    const int ia = pair, ib = 31 - pair;
    const int q0A = ia * 64, q0B = ib * 64;
    const int tid = threadIdx.x, lane = tid & 63, w = tid >> 6;
    const int lg = lane >> 4, lr = lane & 15;
    const float SC = 0.125f * 1.44269504f;       // 1/sqrt(64) * log2(e)

    // Q fragments (B operand): Q[q = q0 + w*16 + lr][d-chunk lg*8 (+32)]
    const bf16* qrA = Qb + ((size_t)bh * 2048 + q0A + w * 16 + lr) * 64;
    bf16x8 qA0 = *(const bf16x8*)(qrA + lg * 8);
    bf16x8 qA1 = *(const bf16x8*)(qrA + 32 + lg * 8);
    const bf16* qrB = Qb + ((size_t)bh * 2048 + q0B + w * 16 + lr) * 64;
    bf16x8 qB0 = *(const bf16x8*)(qrB + lg * 8);
    bf16x8 qB1 = *(const bf16x8*)(qrB + 32 + lg * 8);

    float mA = -1e30f, mB = -1e30f;              // running max, q = lr
    float lA = 0.f,   lB = 0.f;                  // in-lane partial sums
    f32x4 oA[4] = {}, oB[4] = {};                // o[n][j]: d=n*16+lr, q=w*16+lg*4+j

    const int sr = tid >> 2, sp = (tid & 3) * 16;

    auto phase = [&](bf16x8 qf0, bf16x8 qf1, f32x4 (&o)[4], float& l, float& m_,
                     bool diag) {
        f32x4 s[4];
#pragma unroll
        for (int n = 0; n < 4; ++n) {
            bf16x8 kf0 = *(const bf16x8*)(Ks + (n * 16 + lr) * 72 + lg * 8);
            bf16x8 kf1 = *(const bf16x8*)(Ks + (n * 16 + lr) * 72 + 32 + lg * 8);
            f32x4 z = {};
            z = MFMA16(kf0, qf0, z);             // SWAPPED: A=K, B=Q -> S^T
            z = MFMA16(kf1, qf1, z);
            s[n] = z;
        }
        // s[n][j]: k_local = n*16 + lg*4 + j, q_local = lr
        float t = -1e30f;
        if (diag) {
            const int qloc = w * 16 + lr;        // q within tile (j0 == q-tile)
#pragma unroll
            for (int n = 0; n < 4; ++n)
#pragma unroll
                for (int j = 0; j < 4; ++j) {
                    float sv = s[n][j] * SC;
                    if (n * 16 + lg * 4 + j > qloc) sv = -1e30f;
                    s[n][j] = sv;
                    t = fmaxf(t, sv);
                }
        } else {
#pragma unroll
            for (int n = 0; n < 4; ++n)
#pragma unroll
                for (int j = 0; j < 4; ++j) {
                    float sv = s[n][j] * SC;
                    s[n][j] = sv;
                    t = fmaxf(t, sv);
                }
        }
        t = fmaxf(t, __shfl_xor(t, 16));
        t = fmaxf(t, __shfl_xor(t, 32));         // row max for q = lr

        // defer-max (T13, THR=8 in log2 domain)
        if (!__all(t <= m_ + 8.f)) {
            float mn = fmaxf(m_, t);
            float corr = exp2f(m_ - mn);
            m_ = mn;
            l *= corr;
            float cj[4];
#pragma unroll
            for (int j = 0; j < 4; ++j)
                cj[j] = __shfl(corr, (lane & 48) + lg * 4 + j);
#pragma unroll
            for (int n = 0; n < 4; ++n)
#pragma unroll
                for (int j = 0; j < 4; ++j) o[n][j] *= cj[j];
        }
#pragma unroll
        for (int n = 0; n < 4; ++n) {
            bf16x4 pk;
#pragma unroll
            for (int j = 0; j < 4; ++j) {
                float p = exp2f(s[n][j] - m_);
                l += p;
                pk[j] = f2b(p);
            }
            *(bf16x4*)(&Ps[w][lr * 72 + n * 16 + lg * 4]) = pk;
        }
        bf16x8 pf0 = *(const bf16x8*)(&Ps[w][lr * 72 + lg * 8]);
        bf16x8 pf1 = *(const bf16x8*)(&Ps[w][lr * 72 + 32 + lg * 8]);
#pragma unroll
        for (int n = 0; n < 4; ++n) {
            bf16x8 vf0 = *(const bf16x8*)(Vs + (n * 16 + lr) * 72 + lg * 8);
            bf16x8 vf1 = *(const bf16x8*)(Vs + (n * 16 + lr) * 72 + 32 + lg * 8);
            o[n] = MFMA16(pf0, vf0, o[n]);
            o[n] = MFMA16(pf1, vf1, o[n]);
        }
    };

    const int ntiles = ib + 1;
    for (int it = 0; it < ntiles; ++it) {
        const int j0 = it * 64;
        const bf16* ksrc = Kb + ((size_t)bh * 2048 + j0 + sr) * 64 + sp;
        *(int4*)(Ks + sr * 72 + sp)     = *(const int4*)ksrc;
        *(int4*)(Ks + sr * 72 + sp + 8) = *(const int4*)(ksrc + 8);
        const bf16* vsrc = Vt + ((size_t)bh * 64 + sr) * 2048 + j0 + sp;
        *(int4*)(Vs + sr * 72 + sp)     = *(const int4*)vsrc;
        *(int4*)(Vs + sr * 72 + sp + 8) = *(const int4*)(vsrc + 8);
        __syncthreads();

        phase(qB0, qB1, oB, lB, mB, it == ib);
        if (it <= ia) phase(qA0, qA1, oA, lA, mA, it == ia);
        __syncthreads();
    }

    const int b = bh >> 4, h = bh & 15;
    auto wout = [&](f32x4 (&o)[4], float l, int q0) {
        l += __shfl_xor(l, 16);
        l += __shfl_xor(l, 32);                  // full row sum for q = lr
        float linv = 1.f / l;
        float lj[4];
#pragma unroll
        for (int j = 0; j < 4; ++j)
            lj[j] = __shfl(linv, (lane & 48) + lg * 4 + j);
#pragma unroll
        for (int n = 0; n < 4; ++n)
#pragma unroll
            for (int j = 0; j < 4; ++j) {
                int qr = q0 + w * 16 + lg * 4 + j;
                Yb[((size_t)b * 2048 + qr) * 1024 + h * 64 + n * 16 + lr] =
                    f2b(o[n][j] * lj[j]);
            }
    };
    wout(oA, lA, q0A);
    wout(oB, lB, q0B);
}

// ---------------------------------------------------------------------------
// Out GEMM (m97-style): Yb (8192x1024 bf16) @ WoutT^T + bias -> Out f32
// ---------------------------------------------------------------------------
__global__ __launch_bounds__(256) void out_gemm(
    const bf16* __restrict__ Y, const bf16* __restrict__ Wt,
    const float* __restrict__ bias, float* __restrict__ Out)
{
    __shared__ __align__(16) bf16 As[128 * 32];
    __shared__ __align__(16) bf16 Bs[128 * 32];
    const int m0 = blockIdx.x * 128, n0 = blockIdx.y * 128;
    const int tid = threadIdx.x, lane = tid & 63, w = tid >> 6;
    const int wr = (w >> 1) * 64, wc = (w & 1) * 64;
    const int lg = lane >> 4, lr = lane & 15;
    const int srow = tid >> 2, scol = (tid & 3) * 8;
    f32x4 acc[4][4] = {};

    for (int k0 = 0; k0 < 1024; k0 += 32) {
#pragma unroll
        for (int half = 0; half < 2; ++half) {
            const int r = srow + half * 64;
            gload16(Y  + (size_t)(m0 + r) * 1024 + k0 + scol,
                    As + half * 2048 + w * 512);
            gload16(Wt + (size_t)(n0 + r) * 1024 + k0 + scol,
                    Bs + half * 2048 + w * 512);
        }
        __syncthreads();

        bf16x8 af[4], bfr[4];
#pragma unroll
        for (int m = 0; m < 4; ++m)
            af[m] = *(const bf16x8*)(As + (wr + m * 16 + lr) * 32 + lg * 8);
#pragma unroll
        for (int n = 0; n < 4; ++n)
            bfr[n] = *(const bf16x8*)(Bs + (wc + n * 16 + lr) * 32 + lg * 8);
#pragma unroll
        for (int m = 0; m < 4; ++m)
#pragma unroll
            for (int n = 0; n < 4; ++n)
                acc[m][n] = MFMA16(af[m], bfr[n], acc[m][n]);
        __syncthreads();
    }

#pragma unroll
    for (int m = 0; m < 4; ++m)
#pragma unroll
        for (int n = 0; n < 4; ++n)
#pragma unroll
            for (int j = 0; j < 4; ++j) {
                int gm = m0 + wr + m * 16 + lg * 4 + j;
                int gn = n0 + wc + n * 16 + lr;
                Out[(size_t)gm * 1024 + gn] = acc[m][n][j] + bias[gn];
            }
}

// ---------------------------------------------------------------------------
extern "C" void kernel_launch(void* const* d_in, const int* in_sizes, int n_in,
                              void* d_out, int out_size, void* d_ws, size_t ws_size,
                              hipStream_t stream)
{
    const float* x     = (const float*)d_in[0];
    const float* w_qkv = (const float*)d_in[1];
    const float* b_qkv = (const float*)d_in[2];
    const float* w_out = (const float*)d_in[3];
    const float* b_out = (const float*)d_in[4];
    float* out = (float*)d_out;

    char* ws = (char*)d_ws;
    bf16* wqkvT = (bf16*)(ws);                                      //  6.29 MB
    bf16* woutT = (bf16*)(ws + 6291456);                            //  2.10 MB
    bf16* Qb    = (bf16*)(ws + 6291456 + 2097152);                  // 16.78 MB
    bf16* Kb    = (bf16*)(ws + 6291456 + 2097152 + 16777216);       // 16.78 MB
    bf16* Vt    = (bf16*)(ws + 6291456 + 2097152 + 2u * 16777216u); // 16.78 MB
    bf16* Xb    = (bf16*)(ws + 6291456 + 2097152 + 3u * 16777216u); // 16.78 MB
    bf16* Yb    = Xb;  // alias: Xb dead before attn writes Yb

    xcast<<<2048, 256, 0, stream>>>(x, Xb);
    cast_transpose<<<dim3(96, 32), 256, 0, stream>>>(w_qkv, wqkvT, 1024, 3072);
    cast_transpose<<<dim3(32, 32), 256, 0, stream>>>(w_out, woutT, 1024, 1024);
    qkv_gemm<<<dim3(64, 24), 256, 0, stream>>>(Xb, wqkvT, b_qkv, Qb, Kb, Vt);
    attn<<<dim3(16, 64), 256, 0, stream>>>(Qb, Kb, Vt, Yb);
    out_gemm<<<dim3(64, 8), 256, 0, stream>>>(Yb, woutT, b_out, out);
}

// Round 7
// 257.522 us; speedup vs baseline: 1.4108x; 1.0830x over previous
//
#include <hip/hip_runtime.h>
#include <hip/hip_bf16.h>

typedef __bf16 bf16;
typedef __attribute__((__ext_vector_type__(4))) __bf16 bf16x4;
typedef __attribute__((__ext_vector_type__(8))) __bf16 bf16x8;
typedef __attribute__((__ext_vector_type__(4))) float f32x4;

#define MFMA16(a, b, c) __builtin_amdgcn_mfma_f32_16x16x32_bf16(a, b, c, 0, 0, 0)

static __device__ __forceinline__ bf16 f2b(float f) { return (bf16)f; }

// async global->LDS, 16B per lane. Dest must be wave-uniform base (+lane*16 HW).
static __device__ __forceinline__ void gload16(const void* g, void* l) {
    __builtin_amdgcn_global_load_lds(
        (const __attribute__((address_space(1))) int*)g,
        (__attribute__((address_space(3))) int*)l, 16, 0, 0);
}

// ---------------------------------------------------------------------------
// xcast: f32 -> bf16 bulk cast (X -> Xb), 16 elems/thread
// ---------------------------------------------------------------------------
__global__ __launch_bounds__(256) void xcast(
    const float* __restrict__ in, bf16* __restrict__ out)
{
    size_t i = ((size_t)blockIdx.x * 256 + threadIdx.x) * 16;
    float4 a0 = *(const float4*)(in + i);
    float4 a1 = *(const float4*)(in + i + 4);
    float4 a2 = *(const float4*)(in + i + 8);
    float4 a3 = *(const float4*)(in + i + 12);
    bf16x8 p0, p1;
    p0[0] = f2b(a0.x); p0[1] = f2b(a0.y); p0[2] = f2b(a0.z); p0[3] = f2b(a0.w);
    p0[4] = f2b(a1.x); p0[5] = f2b(a1.y); p0[6] = f2b(a1.z); p0[7] = f2b(a1.w);
    p1[0] = f2b(a2.x); p1[1] = f2b(a2.y); p1[2] = f2b(a2.z); p1[3] = f2b(a2.w);
    p1[4] = f2b(a3.x); p1[5] = f2b(a3.y); p1[6] = f2b(a3.z); p1[7] = f2b(a3.w);
    *(bf16x8*)(out + i) = p0;
    *(bf16x8*)(out + i + 8) = p1;
}

// ---------------------------------------------------------------------------
// cast + transpose: in (R x Cc) f32 row-major -> out (Cc x R) bf16 row-major
// ---------------------------------------------------------------------------
__global__ __launch_bounds__(256) void cast_transpose(
    const float* __restrict__ in, bf16* __restrict__ out, int R, int Cc)
{
    __shared__ float tile[32][33];
    const int c0 = blockIdx.x * 32, r0 = blockIdx.y * 32;
    const int tx = threadIdx.x & 31, ty = threadIdx.x >> 5;
#pragma unroll
    for (int i = ty; i < 32; i += 8)
        tile[i][tx] = in[(size_t)(r0 + i) * Cc + c0 + tx];
    __syncthreads();
#pragma unroll
    for (int i = ty; i < 32; i += 8)
        out[(size_t)(c0 + i) * R + r0 + tx] = f2b(tile[tx][i]);
}

// ---------------------------------------------------------------------------
// QKV GEMM (m97-style): Xb (8192x1024 bf16) @ WqkvT^T + bias -> Qb,Kb,Vt
// ---------------------------------------------------------------------------
__global__ __launch_bounds__(256) void qkv_gemm(
    const bf16* __restrict__ Xb, const bf16* __restrict__ Wt,
    const float* __restrict__ bias,
    bf16* __restrict__ Qb, bf16* __restrict__ Kb, bf16* __restrict__ Vt)
{
    __shared__ __align__(16) bf16 As[128 * 32];
    __shared__ __align__(16) bf16 Bs[128 * 32];
    const int m0 = blockIdx.x * 128, n0 = blockIdx.y * 128;
    const int tid = threadIdx.x, lane = tid & 63, w = tid >> 6;
    const int wr = (w >> 1) * 64, wc = (w & 1) * 64;
    const int lg = lane >> 4, lr = lane & 15;
    const int srow = tid >> 2, scol = (tid & 3) * 8;
    f32x4 acc[4][4] = {};

    for (int k0 = 0; k0 < 1024; k0 += 32) {
#pragma unroll
        for (int half = 0; half < 2; ++half) {
            const int r = srow + half * 64;
            gload16(Xb + (size_t)(m0 + r) * 1024 + k0 + scol,
                    As + half * 2048 + w * 512);
            gload16(Wt + (size_t)(n0 + r) * 1024 + k0 + scol,
                    Bs + half * 2048 + w * 512);
        }
        __syncthreads();

        bf16x8 af[4], bfr[4];
#pragma unroll
        for (int m = 0; m < 4; ++m)
            af[m] = *(const bf16x8*)(As + (wr + m * 16 + lr) * 32 + lg * 8);
#pragma unroll
        for (int n = 0; n < 4; ++n)
            bfr[n] = *(const bf16x8*)(Bs + (wc + n * 16 + lr) * 32 + lg * 8);
#pragma unroll
        for (int m = 0; m < 4; ++m)
#pragma unroll
            for (int n = 0; n < 4; ++n)
                acc[m][n] = MFMA16(af[m], bfr[n], acc[m][n]);
        __syncthreads();
    }

#pragma unroll
    for (int m = 0; m < 4; ++m)
#pragma unroll
        for (int n = 0; n < 4; ++n) {
            int gn = n0 + wc + n * 16 + lr;
            int which = gn >> 10, cc = gn & 1023;
            int h = cc >> 6, d = cc & 63;
            float bv = bias[gn];
            if (which == 2) {
                int gm0 = m0 + wr + m * 16 + lg * 4;
                int b = gm0 >> 11, t0 = gm0 & 2047;
                size_t bh = (size_t)(b * 16 + h);
                bf16x4 pk;
#pragma unroll
                for (int j = 0; j < 4; ++j) pk[j] = f2b(acc[m][n][j] + bv);
                *(bf16x4*)(Vt + (bh * 64 + d) * 2048 + t0) = pk;
            } else {
#pragma unroll
                for (int j = 0; j < 4; ++j) {
                    int gm = m0 + wr + m * 16 + lg * 4 + j;
                    int b = gm >> 11, t = gm & 2047;
                    size_t bh = (size_t)(b * 16 + h);
                    bf16 v = f2b(acc[m][n][j] + bv);
                    if (which == 0) Qb[(bh * 2048 + t) * 64 + d] = v;
                    else            Kb[(bh * 2048 + t) * 64 + d] = v;
                }
            }
        }
}

// ---------------------------------------------------------------------------
// Flash attention (causal), triangle-paired, swapped QK^T, XCD-colocated:
//   1D grid, xcd = lid&7 (round-robin assumption); XCD k owns bh in [8k,8k+8)
//   -> per-XCD KV working set = 8 x 512KB = 4MB = one L2.
// ---------------------------------------------------------------------------
__global__ __launch_bounds__(256, 4) void attn(
    const bf16* __restrict__ Qb, const bf16* __restrict__ Kb,
    const bf16* __restrict__ Vt, bf16* __restrict__ Yb)
{
    __shared__ __align__(16) bf16 Ks[64 * 72];
    __shared__ __align__(16) bf16 Vs[64 * 72];
    __shared__ __align__(16) bf16 Ps[4][16 * 72];
    const int lid = blockIdx.x;                  // 0..1023
    const int xcd = lid & 7, idx = lid >> 3;     // round-robin XCD assumption
    const int bh = xcd * 8 + (idx >> 4);         // 8 bh per XCD
    const int pair = idx & 15;                   // 0..15
    const int ia = pair, ib = 31 - pair;
    const int q0A = ia * 64, q0B = ib * 64;
    const int tid = threadIdx.x, lane = tid & 63, w = tid >> 6;
    const int lg = lane >> 4, lr = lane & 15;
    const float SC = 0.125f * 1.44269504f;       // 1/sqrt(64) * log2(e)

    const bf16* qrA = Qb + ((size_t)bh * 2048 + q0A + w * 16 + lr) * 64;
    bf16x8 qA0 = *(const bf16x8*)(qrA + lg * 8);
    bf16x8 qA1 = *(const bf16x8*)(qrA + 32 + lg * 8);
    const bf16* qrB = Qb + ((size_t)bh * 2048 + q0B + w * 16 + lr) * 64;
    bf16x8 qB0 = *(const bf16x8*)(qrB + lg * 8);
    bf16x8 qB1 = *(const bf16x8*)(qrB + 32 + lg * 8);

    float mA = -1e30f, mB = -1e30f;
    float lA = 0.f,   lB = 0.f;
    f32x4 oA[4] = {}, oB[4] = {};

    const int sr = tid >> 2, sp = (tid & 3) * 16;

    auto phase = [&](bf16x8 qf0, bf16x8 qf1, f32x4 (&o)[4], float& l, float& m_,
                     bool diag) {
        f32x4 s[4];
#pragma unroll
        for (int n = 0; n < 4; ++n) {
            bf16x8 kf0 = *(const bf16x8*)(Ks + (n * 16 + lr) * 72 + lg * 8);
            bf16x8 kf1 = *(const bf16x8*)(Ks + (n * 16 + lr) * 72 + 32 + lg * 8);
            f32x4 z = {};
            z = MFMA16(kf0, qf0, z);             // A=K, B=Q -> S^T
            z = MFMA16(kf1, qf1, z);
            s[n] = z;
        }
        float t = -1e30f;
        if (diag) {
            const int qloc = w * 16 + lr;
#pragma unroll
            for (int n = 0; n < 4; ++n)
#pragma unroll
                for (int j = 0; j < 4; ++j) {
                    float sv = s[n][j] * SC;
                    if (n * 16 + lg * 4 + j > qloc) sv = -1e30f;
                    s[n][j] = sv;
                    t = fmaxf(t, sv);
                }
        } else {
#pragma unroll
            for (int n = 0; n < 4; ++n)
#pragma unroll
                for (int j = 0; j < 4; ++j) {
                    float sv = s[n][j] * SC;
                    s[n][j] = sv;
                    t = fmaxf(t, sv);
                }
        }
        t = fmaxf(t, __shfl_xor(t, 16));
        t = fmaxf(t, __shfl_xor(t, 32));

        if (!__all(t <= m_ + 8.f)) {
            float mn = fmaxf(m_, t);
            float corr = exp2f(m_ - mn);
            m_ = mn;
            l *= corr;
            float cj[4];
#pragma unroll
            for (int j = 0; j < 4; ++j)
                cj[j] = __shfl(corr, (lane & 48) + lg * 4 + j);
#pragma unroll
            for (int n = 0; n < 4; ++n)
#pragma unroll
                for (int j = 0; j < 4; ++j) o[n][j] *= cj[j];
        }
#pragma unroll
        for (int n = 0; n < 4; ++n) {
            bf16x4 pk;
#pragma unroll
            for (int j = 0; j < 4; ++j) {
                float p = exp2f(s[n][j] - m_);
                l += p;
                pk[j] = f2b(p);
            }
            *(bf16x4*)(&Ps[w][lr * 72 + n * 16 + lg * 4]) = pk;
        }
        bf16x8 pf0 = *(const bf16x8*)(&Ps[w][lr * 72 + lg * 8]);
        bf16x8 pf1 = *(const bf16x8*)(&Ps[w][lr * 72 + 32 + lg * 8]);
#pragma unroll
        for (int n = 0; n < 4; ++n) {
            bf16x8 vf0 = *(const bf16x8*)(Vs + (n * 16 + lr) * 72 + lg * 8);
            bf16x8 vf1 = *(const bf16x8*)(Vs + (n * 16 + lr) * 72 + 32 + lg * 8);
            o[n] = MFMA16(pf0, vf0, o[n]);
            o[n] = MFMA16(pf1, vf1, o[n]);
        }
    };

    const int ntiles = ib + 1;
    for (int it = 0; it < ntiles; ++it) {
        const int j0 = it * 64;
        const bf16* ksrc = Kb + ((size_t)bh * 2048 + j0 + sr) * 64 + sp;
        *(int4*)(Ks + sr * 72 + sp)     = *(const int4*)ksrc;
        *(int4*)(Ks + sr * 72 + sp + 8) = *(const int4*)(ksrc + 8);
        const bf16* vsrc = Vt + ((size_t)bh * 64 + sr) * 2048 + j0 + sp;
        *(int4*)(Vs + sr * 72 + sp)     = *(const int4*)vsrc;
        *(int4*)(Vs + sr * 72 + sp + 8) = *(const int4*)(vsrc + 8);
        __syncthreads();

        phase(qB0, qB1, oB, lB, mB, it == ib);
        if (it <= ia) phase(qA0, qA1, oA, lA, mA, it == ia);
        __syncthreads();
    }

    const int b = bh >> 4, h = bh & 15;
    auto wout = [&](f32x4 (&o)[4], float l, int q0) {
        l += __shfl_xor(l, 16);
        l += __shfl_xor(l, 32);
        float linv = 1.f / l;
        float lj[4];
#pragma unroll
        for (int j = 0; j < 4; ++j)
            lj[j] = __shfl(linv, (lane & 48) + lg * 4 + j);
#pragma unroll
        for (int n = 0; n < 4; ++n)
#pragma unroll
            for (int j = 0; j < 4; ++j) {
                int qr = q0 + w * 16 + lg * 4 + j;
                Yb[((size_t)b * 2048 + qr) * 1024 + h * 64 + n * 16 + lr] =
                    f2b(o[n][j] * lj[j]);
            }
    };
    wout(oA, lA, q0A);
    wout(oB, lB, q0B);
}

// ---------------------------------------------------------------------------
// Out GEMM (m97-style): Yb (8192x1024 bf16) @ WoutT^T + bias -> Out f32
// ---------------------------------------------------------------------------
__global__ __launch_bounds__(256) void out_gemm(
    const bf16* __restrict__ Y, const bf16* __restrict__ Wt,
    const float* __restrict__ bias, float* __restrict__ Out)
{
    __shared__ __align__(16) bf16 As[128 * 32];
    __shared__ __align__(16) bf16 Bs[128 * 32];
    const int m0 = blockIdx.x * 128, n0 = blockIdx.y * 128;
    const int tid = threadIdx.x, lane = tid & 63, w = tid >> 6;
    const int wr = (w >> 1) * 64, wc = (w & 1) * 64;
    const int lg = lane >> 4, lr = lane & 15;
    const int srow = tid >> 2, scol = (tid & 3) * 8;
    f32x4 acc[4][4] = {};

    for (int k0 = 0; k0 < 1024; k0 += 32) {
#pragma unroll
        for (int half = 0; half < 2; ++half) {
            const int r = srow + half * 64;
            gload16(Y  + (size_t)(m0 + r) * 1024 + k0 + scol,
                    As + half * 2048 + w * 512);
            gload16(Wt + (size_t)(n0 + r) * 1024 + k0 + scol,
                    Bs + half * 2048 + w * 512);
        }
        __syncthreads();

        bf16x8 af[4], bfr[4];
#pragma unroll
        for (int m = 0; m < 4; ++m)
            af[m] = *(const bf16x8*)(As + (wr + m * 16 + lr) * 32 + lg * 8);
#pragma unroll
        for (int n = 0; n < 4; ++n)
            bfr[n] = *(const bf16x8*)(Bs + (wc + n * 16 + lr) * 32 + lg * 8);
#pragma unroll
        for (int m = 0; m < 4; ++m)
#pragma unroll
            for (int n = 0; n < 4; ++n)
                acc[m][n] = MFMA16(af[m], bfr[n], acc[m][n]);
        __syncthreads();
    }

#pragma unroll
    for (int m = 0; m < 4; ++m)
#pragma unroll
        for (int n = 0; n < 4; ++n)
#pragma unroll
            for (int j = 0; j < 4; ++j) {
                int gm = m0 + wr + m * 16 + lg * 4 + j;
                int gn = n0 + wc + n * 16 + lr;
                Out[(size_t)gm * 1024 + gn] = acc[m][n][j] + bias[gn];
            }
}

// ---------------------------------------------------------------------------
extern "C" void kernel_launch(void* const* d_in, const int* in_sizes, int n_in,
                              void* d_out, int out_size, void* d_ws, size_t ws_size,
                              hipStream_t stream)
{
    const float* x     = (const float*)d_in[0];
    const float* w_qkv = (const float*)d_in[1];
    const float* b_qkv = (const float*)d_in[2];
    const float* w_out = (const float*)d_in[3];
    const float* b_out = (const float*)d_in[4];
    float* out = (float*)d_out;

    char* ws = (char*)d_ws;
    bf16* wqkvT = (bf16*)(ws);                                      //  6.29 MB
    bf16* woutT = (bf16*)(ws + 6291456);                            //  2.10 MB
    bf16* Qb    = (bf16*)(ws + 6291456 + 2097152);                  // 16.78 MB
    bf16* Kb    = (bf16*)(ws + 6291456 + 2097152 + 16777216);       // 16.78 MB
    bf16* Vt    = (bf16*)(ws + 6291456 + 2097152 + 2u * 16777216u); // 16.78 MB
    bf16* Xb    = (bf16*)(ws + 6291456 + 2097152 + 3u * 16777216u); // 16.78 MB
    bf16* Yb    = Xb;  // alias: Xb dead before attn writes Yb

    xcast<<<2048, 256, 0, stream>>>(x, Xb);
    cast_transpose<<<dim3(96, 32), 256, 0, stream>>>(w_qkv, wqkvT, 1024, 3072);
    cast_transpose<<<dim3(32, 32), 256, 0, stream>>>(w_out, woutT, 1024, 1024);
    qkv_gemm<<<dim3(64, 24), 256, 0, stream>>>(Xb, wqkvT, b_qkv, Qb, Kb, Vt);
    attn<<<1024, 256, 0, stream>>>(Qb, Kb, Vt, Yb);
    out_gemm<<<dim3(64, 8), 256, 0, stream>>>(Yb, woutT, b_out, out);
}